// Round 14
// baseline (375.198 us; speedup 1.0000x reference)
//
#include <hip/hip_runtime.h>

typedef float f32x4 __attribute__((ext_vector_type(4)));
typedef float f32x16 __attribute__((ext_vector_type(16)));
typedef unsigned short us8 __attribute__((ext_vector_type(8)));

#define DEVINL __device__ __forceinline__

DEVINL unsigned short f2bf(float f) {
  unsigned u = __builtin_bit_cast(unsigned, f);
  u += 0x7fffu + ((u >> 16) & 1u);
  return (unsigned short)(u >> 16);
}
DEVINL float bf2f(unsigned short b) { return __builtin_bit_cast(float, ((unsigned)b) << 16); }
DEVINL us8 ld8(const unsigned short* p) { return *reinterpret_cast<const us8*>(p); }
DEVINL void mfma32(f32x16& acc, us8 a, us8 b) {
  asm("v_mfma_f32_32x32x16_bf16 %0, %1, %2, %0" : "+v"(acc) : "v"(a), "v"(b));
}
DEVINL unsigned cvtpk_bf16(float lo, float hi) {
  unsigned r;
  asm("v_cvt_pk_bf16_f32 %0, %1, %2" : "=v"(r) : "v"(lo), "v"(hi));
  return r;
}
DEVINL us8 us8_from4(unsigned a, unsigned b, unsigned c, unsigned d) {
  union { unsigned u[4]; us8 v; } x;
  x.u[0] = a; x.u[1] = b; x.u[2] = c; x.u[3] = d;
  return x.v;
}
// async global->LDS, 16B per lane; LDS dest = base + lane*16 (wave-uniform base)
DEVINL void gld16(const void* g, void* l) {
  __builtin_amdgcn_global_load_lds((const __attribute__((address_space(1))) void*)g,
                                   (__attribute__((address_space(3))) void*)l, 16, 0, 0);
}

// ---------------- fused prep: all fp32->bf16 converts + bias concat + RoPE tables ------------
DEVINL void cvt4(const float* __restrict__ s, unsigned short* __restrict__ d, long i) {
  float4 v = reinterpret_cast<const float4*>(s)[i];
  unsigned lo = (unsigned)f2bf(v.x) | ((unsigned)f2bf(v.y) << 16);
  unsigned hi = (unsigned)f2bf(v.z) | ((unsigned)f2bf(v.w) << 16);
  reinterpret_cast<uint2*>(d)[i] = make_uint2(lo, hi);
}

__global__ void k_prep(const float* __restrict__ x, const float* __restrict__ wdq,
                       const float* __restrict__ wdkv, const float* __restrict__ wuq,
                       const float* __restrict__ wqr, const float* __restrict__ wuk,
                       const float* __restrict__ wkr, const float* __restrict__ wuv,
                       const float* __restrict__ wo, const float* __restrict__ bdq,
                       const float* __restrict__ bdkv, const float* __restrict__ buq,
                       const float* __restrict__ bqr, const float* __restrict__ buk,
                       const float* __restrict__ bkr, const float* __restrict__ buv,
                       unsigned short* __restrict__ xb, unsigned short* __restrict__ wcd,
                       unsigned short* __restrict__ wcq, unsigned short* __restrict__ wck,
                       unsigned short* __restrict__ wob, float* __restrict__ cosT,
                       float* __restrict__ sinT, float* __restrict__ bcd,
                       float* __restrict__ bcq, float* __restrict__ bck) {
  constexpr long C0 = 2097152, C1 = C0 + 786432, C2 = C1 + 262144, C3 = C2 + 786432,
                 C4 = C3 + 786432, C5 = C4 + 262144, C6 = C5 + 262144, C7 = C6 + 262144,
                 C8 = C7 + 1048576, C9 = C8 + 2097152, C10 = C9 + 3072;
  long u = (long)blockIdx.x * 256 + threadIdx.x;
  if (u < C0) cvt4(x, xb, u);
  else if (u < C1) cvt4(wdq, wcd, u - C0);
  else if (u < C2) cvt4(wdkv, wcd + 1536L * 2048, u - C1);
  else if (u < C3) cvt4(wuq, wcq, u - C2);
  else if (u < C4) cvt4(wqr, wcq + 2048L * 1536, u - C3);
  else if (u < C5) cvt4(wuk, wck, u - C4);
  else if (u < C6) cvt4(wkr, wck + 2048L * 512, u - C5);
  else if (u < C7) cvt4(wuv, wck + 4096L * 512, u - C6);
  else if (u < C8) cvt4(wo, wob, u - C7);
  else if (u < C9) {
    long idx = u - C8;
    int s = (int)(idx >> 10), i = (int)(idx & 1023);
    float e = (float)(2 * i);
    float pw = powf(10000.0f, e);  // overflow->inf -> tn=0, matches fp32 reference
    float tn = 1.0f / (pw / 2048.0f);
    float ang = (float)s * tn;
    cosT[idx] = cosf(ang);
    sinT[idx] = sinf(ang);
  } else if (u < C10) {
    long j4 = (u - C9) * 4;
#pragma unroll
    for (int k = 0; k < 4; ++k) {
      long j = j4 + k;
      if (j < 2048) {
        bcd[j] = j < 1536 ? bdq[j] : bdkv[j - 1536];
      } else if (j < 6144) {
        long jj = j - 2048;
        bcq[jj] = jj < 2048 ? buq[jj] : bqr[jj - 2048];
      } else {
        long jj = j - 6144;
        bck[jj] = jj < 2048 ? buk[jj] : (jj < 4096 ? bkr[jj - 2048] : buv[jj - 4096]);
      }
    }
  }
}

// ---- GEMM: C[M,N] = A[M,K](stride lda) * B[N,K]^T + bias. BM=128 BN=256 BK=32, 8 waves,
// 3-slot rotating LDS pipeline, counted vmcnt (stage lead 2), chunk-XOR swizzle.
// Inner: v_mfma_f32_32x32x16_bf16, wave tile 64x64 as 2x2 blocks of 32x32. ----
template <bool OUTF32>
__global__ __launch_bounds__(512) void k_gemm256(const unsigned short* __restrict__ A,
                                                 const unsigned short* __restrict__ B,
                                                 const float* __restrict__ bias,
                                                 void* __restrict__ Cout, int N, int K, int lda) {
  constexpr int SLOT = 128 * 32 + 256 * 32;  // shorts (A-slot then B-slot)
  __shared__ unsigned short lds[3 * SLOT];
  const int nwg = gridDim.x;
  const int orig = blockIdx.x;
  const int wgid = (orig & 7) * (nwg >> 3) + (orig >> 3);  // XCD-chunked (nwg % 8 == 0)
  const int nbn = N >> 8;
  const int bn = wgid % nbn, bm = wgid / nbn;
  const int tid = threadIdx.x, lane = tid & 63, w = tid >> 6;
  const int r32 = lane & 31, hh = lane >> 5;
  const int wm = w >> 2, wn = w & 3;
  f32x16 acc[2][2] = {};
  const unsigned short* Abase = A + (size_t)bm * 128 * lda;
  const unsigned short* Bbase = B + (size_t)bn * 256 * K;
  const int ra = tid >> 2;
  const int gca = (tid & 3) ^ ((ra >> 1) & 3);
  const int rb1 = (tid + 512) >> 2;
  const int gcb1 = ((tid + 512) & 3) ^ ((rb1 >> 1) & 3);
  const size_t aoff = (size_t)ra * lda + gca * 8;
  const size_t boff0 = (size_t)ra * K + gca * 8;
  const size_t boff1 = (size_t)rb1 * K + gcb1 * 8;
  auto STAGE = [&](int slot, int kt) {
    unsigned short* s = &lds[slot * SLOT];
    gld16(Abase + aoff + kt, s + tid * 8);
    gld16(Bbase + boff0 + kt, s + 128 * 32 + tid * 8);
    gld16(Bbase + boff1 + kt, s + 128 * 32 + (tid + 512) * 8);
  };
  const int nt = K >> 5;
  STAGE(0, 0);
  STAGE(1, 32);
  asm volatile("s_waitcnt vmcnt(3)" ::: "memory");
  asm volatile("s_barrier" ::: "memory");
  for (int t = 0; t < nt; ++t) {
    const int slot = t % 3;
    if (t + 2 < nt) STAGE((t + 2) % 3, (t + 2) * 32);
    const unsigned short* sa = &lds[slot * SLOT];
    const unsigned short* sb = sa + 128 * 32;
    us8 af[2][2], bfr[2][2];  // [m2|n2][kstep]; k = s*16 + hh*8 + e  (chunk s*2+hh)
#pragma unroll
    for (int m2 = 0; m2 < 2; ++m2) {
      int row = wm * 64 + m2 * 32 + r32;
      int sw = (row >> 1) & 3;
#pragma unroll
      for (int s = 0; s < 2; ++s)
        af[m2][s] = ld8(&sa[row * 32 + (((s * 2 + hh) ^ sw) * 8)]);
    }
#pragma unroll
    for (int n2 = 0; n2 < 2; ++n2) {
      int row = wn * 64 + n2 * 32 + r32;
      int sw = (row >> 1) & 3;
#pragma unroll
      for (int s = 0; s < 2; ++s)
        bfr[n2][s] = ld8(&sb[row * 32 + (((s * 2 + hh) ^ sw) * 8)]);
    }
    __builtin_amdgcn_s_setprio(1);
#pragma unroll
    for (int s = 0; s < 2; ++s)
#pragma unroll
      for (int m2 = 0; m2 < 2; ++m2)
#pragma unroll
        for (int n2 = 0; n2 < 2; ++n2) mfma32(acc[m2][n2], af[m2][s], bfr[n2][s]);
    __builtin_amdgcn_s_setprio(0);
    if (t < nt - 2) asm volatile("s_waitcnt vmcnt(3)" ::: "memory");
    else            asm volatile("s_waitcnt vmcnt(0)" ::: "memory");
    asm volatile("s_barrier" ::: "memory");
  }
  // C/D layout (verified m74/m101): col = lane&31, row = (r&3)+8*(r>>2)+4*hh
#pragma unroll
  for (int n2 = 0; n2 < 2; ++n2) {
    int col = bn * 256 + wn * 64 + n2 * 32 + r32;
    float bv = bias[col];
#pragma unroll
    for (int m2 = 0; m2 < 2; ++m2) {
#pragma unroll
      for (int r = 0; r < 16; ++r) {
        int row = bm * 128 + wm * 64 + m2 * 32 + (r & 3) + 8 * (r >> 2) + 4 * hh;
        float vv = acc[m2][n2][r] + bv;
        if (OUTF32)
          reinterpret_cast<float*>(Cout)[(size_t)row * N + col] = vv;
        else
          reinterpret_cast<unsigned short*>(Cout)[(size_t)row * N + col] = f2bf(vv);
      }
    }
  }
}

// ---- k = ct + rope(rl): src row holds [ct (2048) | rl (2048) | ...], width ldin ----
__global__ void k_rope_combine(const unsigned short* __restrict__ src, int ldin,
                               const float* __restrict__ cosT, const float* __restrict__ sinT,
                               unsigned short* __restrict__ outp) {
  int pidx = blockIdx.x * 256 + threadIdx.x;  // pair index
  if (pidx >= 4096 * 1024) return;
  int row = pidx >> 10, i = pidx & 1023;
  int s = row & 2047;
  float c = cosT[s * 1024 + i], sn = sinT[s * 1024 + i];
  const unsigned short* rp = src + (size_t)row * ldin;
  float xe = bf2f(rp[2048 + 2 * i]), xo = bf2f(rp[2048 + 2 * i + 1]);
  float re = xe * c - xo * sn;
  float im = xe * sn + xo * c;
  float q0 = bf2f(rp[2 * i]) + re;
  float q1 = bf2f(rp[2 * i + 1]) + im;
  unsigned pack = (unsigned)f2bf(q0) | ((unsigned)f2bf(q1) << 16);
  *reinterpret_cast<unsigned*>(&outp[(size_t)row * 2048 + 2 * i]) = pack;
}

// ---------------- V transpose: v[4096][cols of width ld] -> vt[b][h][d][s] ----------------
__global__ __launch_bounds__(256) void k_transpose_v(const unsigned short* __restrict__ v, int ld,
                                                     unsigned short* __restrict__ vt) {
  __shared__ unsigned short t[32][33];
  int tx = threadIdx.x & 31, ty = threadIdx.x >> 5;
  int r0 = blockIdx.y * 32, c0 = blockIdx.x * 32;
#pragma unroll
  for (int jj = 0; jj < 4; ++jj)
    t[ty * 4 + jj][tx] = v[(size_t)(r0 + ty * 4 + jj) * ld + c0 + tx];
  __syncthreads();
  int b = r0 >> 11;
#pragma unroll
  for (int jj = 0; jj < 4; ++jj) {
    int colc = c0 + ty * 4 + jj;
    size_t orow = (size_t)(b * 16 + (colc >> 7)) * 128 + (colc & 127);
    vt[orow * 2048 + (r0 & 2047) + tx] = t[tx][ty * 4 + jj];
  }
}

// ------ flash attention, 32x32 MFMA: 8 waves x 32 q-rows (q-tile 256), KV tile 64 ------
// Q read from t12 ([q_ct | rope_raw], ldin 4096) with fused RoPE and *SC2 pre-scale.
// C/D layout: col=lane&31, row=(reg&3)+8*(reg>>2)+4*(lane>>5).
// Grid: 256 blocks, XCD-chunked so each XCD owns 4 (h,b) groups (KV L2-resident).
__global__ __launch_bounds__(512, 1) void k_attn(const unsigned short* __restrict__ Qsrc,
                                                 const unsigned short* __restrict__ Kg,
                                                 const unsigned short* __restrict__ VT,
                                                 const float* __restrict__ cosT,
                                                 const float* __restrict__ sinT,
                                                 unsigned short* __restrict__ Aout) {
  __shared__ unsigned short Ks[2][64 * 128];
  __shared__ unsigned short VTs[2][128 * 64];
  const int tid = threadIdx.x, lane = tid & 63, w = tid >> 6;  // w in [0,8)
  const int hh = lane >> 5, q32 = lane & 31;
  // numerics-neutral block remap: blocks independent; only locality changes
  const int orig = blockIdx.x;
  const int wgid = (orig & 7) * 32 + (orig >> 3);
  const int qt = wgid & 7;       // q-tile 256 rows
  const int hb = wgid >> 3;      // 0..31: 4 consecutive per XCD
  const int h = hb & 15, b = hb >> 4;
  const float SC2 = 0.08838834764831845f * 1.4426950408889634f;  // (1/sqrt(128))*log2(e)
  const int srow = qt * 256 + w * 32 + q32;  // seq position
  // ---- Q load with fused RoPE: qf[ds] = Q[q=q32][d = ds*16 + hh*8 + 0..7] ----
  us8 qf[8];
  {
    const unsigned short* Qr = Qsrc + ((size_t)b * 2048 + srow) * 4096;
#pragma unroll
    for (int ds = 0; ds < 8; ++ds) {
      int dcol = h * 128 + ds * 16 + hh * 8;
      us8 c8 = ld8(&Qr[dcol]);
      us8 r8 = ld8(&Qr[2048 + dcol]);
      unsigned wv[4];
#pragma unroll
      for (int p2 = 0; p2 < 4; ++p2) {
        int i = (dcol >> 1) + p2;
        float cc = cosT[srow * 1024 + i], ss = sinT[srow * 1024 + i];
        float xe = bf2f(r8[2 * p2]), xo = bf2f(r8[2 * p2 + 1]);
        float o0 = (bf2f(c8[2 * p2]) + xe * cc - xo * ss) * SC2;
        float o1 = (bf2f(c8[2 * p2 + 1]) + xe * ss + xo * cc) * SC2;
        wv[p2] = cvtpk_bf16(o0, o1);
      }
      qf[ds] = us8_from4(wv[0], wv[1], wv[2], wv[3]);
    }
  }
  f32x16 O[4] = {};
  float mq = -1e30f, lq = 0.f;
  const unsigned short* Kbase = Kg + (size_t)b * 2048 * 2048 + h * 128;
  const unsigned short* VTb = VT + (size_t)(b * 16 + h) * 128 * 2048;
  auto STAGE = [&](int bufi, int ktrow) {
#pragma unroll
    for (int j = 0; j < 2; ++j) {
      int ch = (j * 8 + w) * 64 + lane;  // 16B chunk id in [0,1024)
      int key = ch >> 4, cp = ch & 15;   // K tile: 64 rows x 16 chunks, XOR key&15
      gld16(&Kbase[(size_t)(ktrow + key) * 2048 + (size_t)((cp ^ (key & 15)) * 8)],
            &Ks[bufi][(j * 8 + w) * 512]);
      int d = ch >> 3, c2 = ch & 7;      // VT tile: 128 rows x 8 chunks, XOR d&7
      gld16(&VTb[(size_t)d * 2048 + ktrow + (size_t)((c2 ^ (d & 7)) * 8)],
            &VTs[bufi][(j * 8 + w) * 512]);
    }
  };
  STAGE(0, 0);
  for (int t = 0; t < 32; ++t) {
    const int cur = t & 1;
    __syncthreads();
    if (t < 31) STAGE(cur ^ 1, (t + 1) * 64);
    // ---- QK^T swapped: S2[kb] reg r = S[key = kb*32 + (r&3)+8*(r>>2)+4*hh][q = q32] ----
    f32x16 S2[2] = {};
    __builtin_amdgcn_s_setprio(1);
#pragma unroll
    for (int kb = 0; kb < 2; ++kb) {
      const int key = kb * 32 + q32;
      const int swz = key & 15;
#pragma unroll
      for (int ds = 0; ds < 8; ++ds) {
        us8 kf = ld8(&Ks[cur][key * 128 + (((ds * 2 + hh) ^ swz) * 8)]);
        mfma32(S2[kb], kf, qf[ds]);
      }
    }
    __builtin_amdgcn_s_setprio(0);
    // ---- softmax (per q = q32; both halves hold same stats after xor-32 reduce) ----
    float mx[16];
#pragma unroll
    for (int r = 0; r < 16; ++r) mx[r] = fmaxf(S2[0][r], S2[1][r]);
#pragma unroll
    for (int st = 8; st > 0; st >>= 1)
#pragma unroll
      for (int r = 0; r < st; ++r) mx[r] = fmaxf(mx[r], mx[r + st]);
    float smax = fmaxf(mx[0], __shfl_xor(mx[0], 32));
    if (!__all(smax <= mq + 8.0f)) {  // defer-max
      float mn = fmaxf(mq, smax);
      float fac = exp2f(mq - mn);
      lq *= fac;
      mq = mn;
#pragma unroll
      for (int r = 0; r < 16; ++r) {
        int qr = (r & 3) + 8 * (r >> 2) + 4 * hh;
        float fr = __shfl(fac, qr);
#pragma unroll
        for (int db = 0; db < 4; ++db) O[db][r] *= fr;
      }
    }
    float ps = 0.f;
    unsigned pk[2][8];
#pragma unroll
    for (int kb = 0; kb < 2; ++kb) {
      float e[16];
#pragma unroll
      for (int r = 0; r < 16; ++r) {
        e[r] = exp2f(S2[kb][r] - mq);
        ps += e[r];
      }
#pragma unroll
      for (int pp = 0; pp < 8; ++pp) pk[kb][pp] = cvtpk_bf16(e[2 * pp], e[2 * pp + 1]);
    }
    ps += __shfl_xor(ps, 32);
    lq += ps;
    // ---- PV: build A-frags in-register (elem e <-> key ks*16 + 8*half + e) ----
    __builtin_amdgcn_s_setprio(1);
#pragma unroll
    for (int ks = 0; ks < 4; ++ks) {
      const int kb = ks >> 1, kk = ks & 1;
      unsigned u_own = hh ? pk[kb][4 * kk + 2] : pk[kb][4 * kk + 0];
      unsigned v_own = hh ? pk[kb][4 * kk + 3] : pk[kb][4 * kk + 1];
      unsigned u_snd = hh ? pk[kb][4 * kk + 0] : pk[kb][4 * kk + 2];
      unsigned v_snd = hh ? pk[kb][4 * kk + 1] : pk[kb][4 * kk + 3];
      unsigned uo = (unsigned)__shfl_xor((int)u_snd, 32);
      unsigned vo = (unsigned)__shfl_xor((int)v_snd, 32);
      us8 pa = us8_from4(hh ? uo : u_own, hh ? vo : v_own, hh ? u_own : uo, hh ? v_own : vo);
#pragma unroll
      for (int db = 0; db < 4; ++db) {
        int d = db * 32 + q32;
        us8 vf = ld8(&VTs[cur][d * 64 + (((ks * 2 + hh) ^ (d & 7)) * 8)]);
        mfma32(O[db], pa, vf);
      }
    }
    __builtin_amdgcn_s_setprio(0);
  }
  // ---- epilogue: O[db] reg r -> row q = (r&3)+8*(r>>2)+4*hh, col d = db*32 + q32 ----
  float inv = 1.0f / lq;
#pragma unroll
  for (int r = 0; r < 16; ++r) {
    int qr = (r & 3) + 8 * (r >> 2) + 4 * hh;
    float ir = __shfl(inv, qr);
    size_t row = (size_t)b * 2048 + qt * 256 + w * 32 + qr;
#pragma unroll
    for (int db = 0; db < 4; ++db)
      Aout[row * 2048 + h * 128 + db * 32 + q32] = f2bf(O[db][r] * ir);
  }
}

extern "C" void kernel_launch(void* const* d_in, const int* in_sizes, int n_in, void* d_out,
                              int out_size, void* d_ws, size_t ws_size, hipStream_t stream) {
  (void)in_sizes; (void)n_in; (void)out_size; (void)ws_size;
  constexpr int Mr = 4096;
  using US = unsigned short;
  const float* x        = (const float*)d_in[0];
  const float* w_down_q = (const float*)d_in[1];
  const float* b_down_q = (const float*)d_in[2];
  const float* w_up_q   = (const float*)d_in[3];
  const float* b_up_q   = (const float*)d_in[4];
  const float* w_down_kv= (const float*)d_in[5];
  const float* b_down_kv= (const float*)d_in[6];
  const float* w_up_k   = (const float*)d_in[7];
  const float* b_up_k   = (const float*)d_in[8];
  const float* w_up_v   = (const float*)d_in[9];
  const float* b_up_v   = (const float*)d_in[10];
  const float* wq_r     = (const float*)d_in[11];
  const float* bq_r     = (const float*)d_in[12];
  const float* wk_r     = (const float*)d_in[13];
  const float* bk_r     = (const float*)d_in[14];
  const float* wo       = (const float*)d_in[15];
  const float* bo       = (const float*)d_in[16];

  char* p = (char*)d_ws;
  auto alloc = [&](size_t bytes) { char* r = p; p += (bytes + 255) & ~(size_t)255; return r; };
  // ---- round-9 proven layout: persistent buffers FIRST, aliasable region LAST ----
  float* cosT      = (float*)alloc((size_t)2048 * 1024 * 4);          //  8 MB
  float* sinT      = (float*)alloc((size_t)2048 * 1024 * 4);          //  8 MB
  US* wcat_kvup    = (US*)alloc((size_t)6144 * 512 * 2);              //  6 MB (live in G_kvup)
  US* wob          = (US*)alloc((size_t)2048 * 2048 * 2);             //  8 MB (live to G_out)
  US* ct           = (US*)alloc((size_t)Mr * 2048 * 2);               // 16 MB; aliased by aout
  US* t12          = (US*)alloc((size_t)Mr * 4096 * 2);               // 32 MB (live into attn)
  US* vtb          = (US*)alloc((size_t)Mr * 2048 * 2);               // 16 MB
  US* kb           = (US*)alloc((size_t)Mr * 2048 * 2);               // 16 MB
  float* bcat_down = (float*)alloc(2048 * 4);
  float* bcat_qup  = (float*)alloc(4096 * 4);
  float* bcat_kvup = (float*)alloc(6144 * 4);
  US* xb           = (US*)alloc((size_t)Mr * 2048 * 2);               // 16 MB }
  US* wcat_down    = (US*)alloc((size_t)2048 * 2048 * 2);             //  8 MB } kv3 (48MB)
  US* wcat_qup     = (US*)alloc((size_t)4096 * 1536 * 2);             // 12 MB } overlays
  alloc((size_t)12 * 1024 * 1024);                                    // 12 MB } tail pad
  US* kv3  = xb;    // 48MB = xb(16)+wcat_down(8)+wcat_qup(12)+pad(12); all dead before G_kvup
  US* aout = ct;    // ct dead after G_kvup

  // one fused prep dispatch: 9 cvts + freqs + bias concats
  k_prep<<<dim3(33804), dim3(256), 0, stream>>>(
      x, w_down_q, w_down_kv, w_up_q, wq_r, w_up_k, wk_r, w_up_v, wo, b_down_q, b_down_kv,
      b_up_q, bq_r, b_up_k, bk_r, b_up_v, xb, wcat_down, wcat_qup, wcat_kvup, wob, cosT, sinT,
      bcat_down, bcat_qup, bcat_kvup);

  // down-projection: ct = x . [wdq; wdkv]^T   (256 blocks)
  k_gemm256<false><<<dim3((2048 / 256) * (Mr / 128)), dim3(512), 0, stream>>>(
      xb, wcat_down, bcat_down, (void*)ct, 2048, 2048, 2048);
  // q up-projection: t12 = ctq . [wuq; wqr]^T  (512 blocks)
  k_gemm256<false><<<dim3((4096 / 256) * (Mr / 128)), dim3(512), 0, stream>>>(
      ct, wcat_qup, bcat_qup, (void*)t12, 4096, 1536, 2048);
  // kv up-projection: kv3 = ctkv . [wuk; wkr; wuv]^T  (768 blocks)
  k_gemm256<false><<<dim3((6144 / 256) * (Mr / 128)), dim3(512), 0, stream>>>(
      ct + 1536, wcat_kvup, bcat_kvup, (void*)kv3, 6144, 512, 2048);
  k_rope_combine<<<dim3((4096 * 1024 + 255) / 256), dim3(256), 0, stream>>>(kv3, 6144, cosT, sinT,
                                                                            kb);
  k_transpose_v<<<dim3(64, 128), dim3(256), 0, stream>>>(kv3 + 4096, 6144, vtb);
  // attention (q-RoPE fused) -> aout   [256 blocks x 512 thr, XCD-chunked KV L2 residency]
  k_attn<<<dim3(256), dim3(512), 0, stream>>>(t12, kb, vtb, cosT, sinT, aout);
  // output projection (f32 out, 256 blocks)
  k_gemm256<true><<<dim3((2048 / 256) * (Mr / 128)), dim3(512), 0, stream>>>(
      aout, wob, bo, d_out, 2048, 2048, 2048);
}

// Round 15
// 359.526 us; speedup vs baseline: 1.0436x; 1.0436x over previous
//
#include <hip/hip_runtime.h>

typedef float f32x4 __attribute__((ext_vector_type(4)));
typedef float f32x16 __attribute__((ext_vector_type(16)));
typedef unsigned short us8 __attribute__((ext_vector_type(8)));

#define DEVINL __device__ __forceinline__

DEVINL unsigned short f2bf(float f) {
  unsigned u = __builtin_bit_cast(unsigned, f);
  u += 0x7fffu + ((u >> 16) & 1u);
  return (unsigned short)(u >> 16);
}
DEVINL float bf2f(unsigned short b) { return __builtin_bit_cast(float, ((unsigned)b) << 16); }
DEVINL us8 ld8(const unsigned short* p) { return *reinterpret_cast<const us8*>(p); }
DEVINL void mfma16(f32x4& acc, us8 a, us8 b) {
  asm("v_mfma_f32_16x16x32_bf16 %0, %1, %2, %0" : "+v"(acc) : "v"(a), "v"(b));
}
DEVINL void mfma32(f32x16& acc, us8 a, us8 b) {
  asm("v_mfma_f32_32x32x16_bf16 %0, %1, %2, %0" : "+v"(acc) : "v"(a), "v"(b));
}
DEVINL unsigned cvtpk_bf16(float lo, float hi) {
  unsigned r;
  asm("v_cvt_pk_bf16_f32 %0, %1, %2" : "=v"(r) : "v"(lo), "v"(hi));
  return r;
}
DEVINL us8 us8_from4(unsigned a, unsigned b, unsigned c, unsigned d) {
  union { unsigned u[4]; us8 v; } x;
  x.u[0] = a; x.u[1] = b; x.u[2] = c; x.u[3] = d;
  return x.v;
}
// async global->LDS, 16B per lane; LDS dest = base + lane*16 (wave-uniform base)
DEVINL void gld16(const void* g, void* l) {
  __builtin_amdgcn_global_load_lds((const __attribute__((address_space(1))) void*)g,
                                   (__attribute__((address_space(3))) void*)l, 16, 0, 0);
}

// ---------------- fused prep: all fp32->bf16 converts + bias concat + RoPE tables ------------
DEVINL void cvt4(const float* __restrict__ s, unsigned short* __restrict__ d, long i) {
  float4 v = reinterpret_cast<const float4*>(s)[i];
  unsigned lo = (unsigned)f2bf(v.x) | ((unsigned)f2bf(v.y) << 16);
  unsigned hi = (unsigned)f2bf(v.z) | ((unsigned)f2bf(v.w) << 16);
  reinterpret_cast<uint2*>(d)[i] = make_uint2(lo, hi);
}

__global__ void k_prep(const float* __restrict__ x, const float* __restrict__ wdq,
                       const float* __restrict__ wdkv, const float* __restrict__ wuq,
                       const float* __restrict__ wqr, const float* __restrict__ wuk,
                       const float* __restrict__ wkr, const float* __restrict__ wuv,
                       const float* __restrict__ wo, const float* __restrict__ bdq,
                       const float* __restrict__ bdkv, const float* __restrict__ buq,
                       const float* __restrict__ bqr, const float* __restrict__ buk,
                       const float* __restrict__ bkr, const float* __restrict__ buv,
                       unsigned short* __restrict__ xb, unsigned short* __restrict__ wcd,
                       unsigned short* __restrict__ wcq, unsigned short* __restrict__ wck,
                       unsigned short* __restrict__ wob, float* __restrict__ cosT,
                       float* __restrict__ sinT, float* __restrict__ bcd,
                       float* __restrict__ bcq, float* __restrict__ bck) {
  constexpr long C0 = 2097152, C1 = C0 + 786432, C2 = C1 + 262144, C3 = C2 + 786432,
                 C4 = C3 + 786432, C5 = C4 + 262144, C6 = C5 + 262144, C7 = C6 + 262144,
                 C8 = C7 + 1048576, C9 = C8 + 2097152, C10 = C9 + 3072;
  long u = (long)blockIdx.x * 256 + threadIdx.x;
  if (u < C0) cvt4(x, xb, u);
  else if (u < C1) cvt4(wdq, wcd, u - C0);
  else if (u < C2) cvt4(wdkv, wcd + 1536L * 2048, u - C1);
  else if (u < C3) cvt4(wuq, wcq, u - C2);
  else if (u < C4) cvt4(wqr, wcq + 2048L * 1536, u - C3);
  else if (u < C5) cvt4(wuk, wck, u - C4);
  else if (u < C6) cvt4(wkr, wck + 2048L * 512, u - C5);
  else if (u < C7) cvt4(wuv, wck + 4096L * 512, u - C6);
  else if (u < C8) cvt4(wo, wob, u - C7);
  else if (u < C9) {
    long idx = u - C8;
    int s = (int)(idx >> 10), i = (int)(idx & 1023);
    float e = (float)(2 * i);
    float pw = powf(10000.0f, e);  // overflow->inf -> tn=0, matches fp32 reference
    float tn = 1.0f / (pw / 2048.0f);
    float ang = (float)s * tn;
    cosT[idx] = cosf(ang);
    sinT[idx] = sinf(ang);
  } else if (u < C10) {
    long j4 = (u - C9) * 4;
#pragma unroll
    for (int k = 0; k < 4; ++k) {
      long j = j4 + k;
      if (j < 2048) {
        bcd[j] = j < 1536 ? bdq[j] : bdkv[j - 1536];
      } else if (j < 6144) {
        long jj = j - 2048;
        bcq[jj] = jj < 2048 ? buq[jj] : bqr[jj - 2048];
      } else {
        long jj = j - 6144;
        bck[jj] = jj < 2048 ? buk[jj] : (jj < 4096 ? bkr[jj - 2048] : buv[jj - 4096]);
      }
    }
  }
}

// ---- GEMM: C[M,N] = A[M,K](stride lda) * B[N,K]^T + bias. BM=128 BN=256 BK=32,
// 4 waves (2x2), wave tile 64x128 (12 ds_read_b128 per 32 MFMA), 3-slot rotating LDS
// pipeline with counted vmcnt (stage lead 2, 6 loads/thread/stage), chunk-XOR swizzle. ----
template <bool OUTF32>
__global__ __launch_bounds__(256) void k_gemm256(const unsigned short* __restrict__ A,
                                                 const unsigned short* __restrict__ B,
                                                 const float* __restrict__ bias,
                                                 void* __restrict__ Cout, int N, int K, int lda) {
  constexpr int SLOT = 128 * 32 + 256 * 32;  // shorts (A-slot then B-slot)
  __shared__ unsigned short lds[3 * SLOT];
  const int nwg = gridDim.x;
  const int orig = blockIdx.x;
  const int wgid = (orig & 7) * (nwg >> 3) + (orig >> 3);  // XCD-chunked (nwg % 8 == 0)
  const int nbn = N >> 8;
  const int bn = wgid % nbn, bm = wgid / nbn;
  const int tid = threadIdx.x, lane = tid & 63, w = tid >> 6;
  const int g = lane >> 4, l16 = lane & 15;
  const int wm = w >> 1, wn = w & 1;
  f32x4 acc[4][8] = {};
  const unsigned short* Abase = A + (size_t)bm * 128 * lda;
  const unsigned short* Bbase = B + (size_t)bn * 256 * K;
  // staging: 1536 chunks (A 512, B 1024), 256 threads x 6; LDS chunk c <- global col-chunk
  // (c&3)^((row>>1)&3)  [involution]
  size_t aoff[2], boff[4];
#pragma unroll
  for (int j = 0; j < 2; ++j) {
    int c = j * 256 + tid;
    int row = c >> 2, gc = (c & 3) ^ ((row >> 1) & 3);
    aoff[j] = (size_t)row * lda + gc * 8;
  }
#pragma unroll
  for (int j = 0; j < 4; ++j) {
    int cb = j * 256 + tid;
    int row = cb >> 2, gc = (cb & 3) ^ ((row >> 1) & 3);
    boff[j] = (size_t)row * K + gc * 8;
  }
  auto STAGE = [&](int slot, int kt) {
    unsigned short* s = &lds[slot * SLOT];
#pragma unroll
    for (int j = 0; j < 2; ++j) gld16(Abase + aoff[j] + kt, s + (j * 256 + tid) * 8);
#pragma unroll
    for (int j = 0; j < 4; ++j)
      gld16(Bbase + boff[j] + kt, s + 128 * 32 + (j * 256 + tid) * 8);
  };
  const int nt = K >> 5;
  STAGE(0, 0);
  STAGE(1, 32);
  asm volatile("s_waitcnt vmcnt(6)" ::: "memory");
  asm volatile("s_barrier" ::: "memory");
  for (int t = 0; t < nt; ++t) {
    const int slot = t % 3;
    if (t + 2 < nt) STAGE((t + 2) % 3, (t + 2) * 32);
    const unsigned short* sa = &lds[slot * SLOT];
    const unsigned short* sb = sa + 128 * 32;
    us8 af[4], bf[8];
#pragma unroll
    for (int m = 0; m < 4; ++m) {
      int row = wm * 64 + m * 16 + l16;
      af[m] = ld8(&sa[row * 32 + ((g ^ ((row >> 1) & 3)) * 8)]);
    }
#pragma unroll
    for (int n = 0; n < 8; ++n) {
      int row = wn * 128 + n * 16 + l16;
      bf[n] = ld8(&sb[row * 32 + ((g ^ ((row >> 1) & 3)) * 8)]);
    }
    __builtin_amdgcn_s_setprio(1);
#pragma unroll
    for (int m = 0; m < 4; ++m)
#pragma unroll
      for (int n = 0; n < 8; ++n) mfma16(acc[m][n], af[m], bf[n]);
    __builtin_amdgcn_s_setprio(0);
    if (t < nt - 2) asm volatile("s_waitcnt vmcnt(6)" ::: "memory");
    else            asm volatile("s_waitcnt vmcnt(0)" ::: "memory");
    asm volatile("s_barrier" ::: "memory");
  }
#pragma unroll
  for (int n = 0; n < 8; ++n) {
    int col = bn * 256 + wn * 128 + n * 16 + l16;
    float bv = bias[col];
#pragma unroll
    for (int m = 0; m < 4; ++m) {
      int row0 = bm * 128 + wm * 64 + m * 16 + g * 4;
#pragma unroll
      for (int r = 0; r < 4; ++r) {
        float vv = acc[m][n][r] + bv;
        if (OUTF32)
          reinterpret_cast<float*>(Cout)[(size_t)(row0 + r) * N + col] = vv;
        else
          reinterpret_cast<unsigned short*>(Cout)[(size_t)(row0 + r) * N + col] = f2bf(vv);
      }
    }
  }
}

// ---- k = ct + rope(rl): src row holds [ct (2048) | rl (2048) | ...], width ldin ----
__global__ void k_rope_combine(const unsigned short* __restrict__ src, int ldin,
                               const float* __restrict__ cosT, const float* __restrict__ sinT,
                               unsigned short* __restrict__ outp) {
  int pidx = blockIdx.x * 256 + threadIdx.x;  // pair index
  if (pidx >= 4096 * 1024) return;
  int row = pidx >> 10, i = pidx & 1023;
  int s = row & 2047;
  float c = cosT[s * 1024 + i], sn = sinT[s * 1024 + i];
  const unsigned short* rp = src + (size_t)row * ldin;
  float xe = bf2f(rp[2048 + 2 * i]), xo = bf2f(rp[2048 + 2 * i + 1]);
  float re = xe * c - xo * sn;
  float im = xe * sn + xo * c;
  float q0 = bf2f(rp[2 * i]) + re;
  float q1 = bf2f(rp[2 * i + 1]) + im;
  unsigned pack = (unsigned)f2bf(q0) | ((unsigned)f2bf(q1) << 16);
  *reinterpret_cast<unsigned*>(&outp[(size_t)row * 2048 + 2 * i]) = pack;
}

// ---------------- V transpose: v[4096][cols of width ld] -> vt[b][h][d][s] ----------------
__global__ __launch_bounds__(256) void k_transpose_v(const unsigned short* __restrict__ v, int ld,
                                                     unsigned short* __restrict__ vt) {
  __shared__ unsigned short t[32][33];
  int tx = threadIdx.x & 31, ty = threadIdx.x >> 5;
  int r0 = blockIdx.y * 32, c0 = blockIdx.x * 32;
#pragma unroll
  for (int jj = 0; jj < 4; ++jj)
    t[ty * 4 + jj][tx] = v[(size_t)(r0 + ty * 4 + jj) * ld + c0 + tx];
  __syncthreads();
  int b = r0 >> 11;
#pragma unroll
  for (int jj = 0; jj < 4; ++jj) {
    int colc = c0 + ty * 4 + jj;
    size_t orow = (size_t)(b * 16 + (colc >> 7)) * 128 + (colc & 127);
    vt[orow * 2048 + (r0 & 2047) + tx] = t[tx][ty * 4 + jj];
  }
}

// ------ flash attention, 32x32 MFMA: 4 waves x 32 q-rows, KV tile 64, in-register P ------
// Q read from t12 ([q_ct | rope_raw], ldin 4096) with fused RoPE and *SC2 pre-scale.
// C/D layout (m74/m101): col=lane&31, row=(reg&3)+8*(reg>>2)+4*(lane>>5).
// Grid: 1-D 512 blocks, XCD-chunked so each XCD owns 4 (h,b) groups (KV L2-resident).
__global__ __launch_bounds__(256, 2) void k_attn(const unsigned short* __restrict__ Qsrc,
                                                 const unsigned short* __restrict__ Kg,
                                                 const unsigned short* __restrict__ VT,
                                                 const float* __restrict__ cosT,
                                                 const float* __restrict__ sinT,
                                                 unsigned short* __restrict__ Aout) {
  __shared__ unsigned short Ks[2][64 * 128];
  __shared__ unsigned short VTs[2][128 * 64];
  const int tid = threadIdx.x, lane = tid & 63, w = tid >> 6;
  const int hh = lane >> 5, q32 = lane & 31;
  // numerics-neutral block remap: blocks independent; only locality changes
  const int orig = blockIdx.x;
  const int wgid = (orig & 7) * 64 + (orig >> 3);
  const int qt = wgid & 15;
  const int hb = wgid >> 4;      // 0..31: 4 consecutive per XCD
  const int h = hb & 15, b = hb >> 4;
  const float SC2 = 0.08838834764831845f * 1.4426950408889634f;  // (1/sqrt(128))*log2(e)
  const int srow = qt * 128 + w * 32 + q32;  // seq position
  // ---- Q load with fused RoPE: qf[ds] = Q[q=q32][d = ds*16 + hh*8 + 0..7] ----
  us8 qf[8];
  {
    const unsigned short* Qr = Qsrc + ((size_t)b * 2048 + srow) * 4096;
#pragma unroll
    for (int ds = 0; ds < 8; ++ds) {
      int dcol = h * 128 + ds * 16 + hh * 8;
      us8 c8 = ld8(&Qr[dcol]);
      us8 r8 = ld8(&Qr[2048 + dcol]);
      unsigned wv[4];
#pragma unroll
      for (int p2 = 0; p2 < 4; ++p2) {
        int i = (dcol >> 1) + p2;
        float cc = cosT[srow * 1024 + i], ss = sinT[srow * 1024 + i];
        float xe = bf2f(r8[2 * p2]), xo = bf2f(r8[2 * p2 + 1]);
        float o0 = (bf2f(c8[2 * p2]) + xe * cc - xo * ss) * SC2;
        float o1 = (bf2f(c8[2 * p2 + 1]) + xe * ss + xo * cc) * SC2;
        wv[p2] = cvtpk_bf16(o0, o1);
      }
      qf[ds] = us8_from4(wv[0], wv[1], wv[2], wv[3]);
    }
  }
  f32x16 O[4] = {};
  float mq = -1e30f, lq = 0.f;
  const unsigned short* Kbase = Kg + (size_t)b * 2048 * 2048 + h * 128;
  const unsigned short* VTb = VT + (size_t)(b * 16 + h) * 128 * 2048;
  auto STAGE = [&](int bufi, int ktrow) {
#pragma unroll
    for (int j = 0; j < 4; ++j) {
      int ch = (j * 4 + w) * 64 + lane;
      int key = ch >> 4, cp = ch & 15;  // K tile: 64 rows x 16 chunks, XOR key&15
      gld16(&Kbase[(size_t)(ktrow + key) * 2048 + (size_t)((cp ^ (key & 15)) * 8)],
            &Ks[bufi][(j * 4 + w) * 512]);
      int d = ch >> 3, c2 = ch & 7;     // VT tile: 128 rows x 8 chunks, XOR d&7
      gld16(&VTb[(size_t)d * 2048 + ktrow + (size_t)((c2 ^ (d & 7)) * 8)],
            &VTs[bufi][(j * 4 + w) * 512]);
    }
  };
  STAGE(0, 0);
  for (int t = 0; t < 32; ++t) {
    const int cur = t & 1;
    __syncthreads();
    if (t < 31) STAGE(cur ^ 1, (t + 1) * 64);
    // ---- QK^T swapped: S2[kb] reg r = S[key = kb*32 + (r&3)+8*(r>>2)+4*hh][q = q32] ----
    f32x16 S2[2] = {};
    __builtin_amdgcn_s_setprio(1);
#pragma unroll
    for (int kb = 0; kb < 2; ++kb) {
      const int key = kb * 32 + q32;
      const int swz = key & 15;
#pragma unroll
      for (int ds = 0; ds < 8; ++ds) {
        us8 kf = ld8(&Ks[cur][key * 128 + (((ds * 2 + hh) ^ swz) * 8)]);
        mfma32(S2[kb], kf, qf[ds]);
      }
    }
    __builtin_amdgcn_s_setprio(0);
    // ---- softmax (per q = q32; both halves hold same stats after xor-32 reduce) ----
    float mx[16];
#pragma unroll
    for (int r = 0; r < 16; ++r) mx[r] = fmaxf(S2[0][r], S2[1][r]);
#pragma unroll
    for (int st = 8; st > 0; st >>= 1)
#pragma unroll
      for (int r = 0; r < st; ++r) mx[r] = fmaxf(mx[r], mx[r + st]);
    float smax = fmaxf(mx[0], __shfl_xor(mx[0], 32));
    if (!__all(smax <= mq + 8.0f)) {  // defer-max
      float mn = fmaxf(mq, smax);
      float fac = exp2f(mq - mn);
      lq *= fac;
      mq = mn;
#pragma unroll
      for (int r = 0; r < 16; ++r) {
        int qr = (r & 3) + 8 * (r >> 2) + 4 * hh;
        float fr = __shfl(fac, qr);
#pragma unroll
        for (int db = 0; db < 4; ++db) O[db][r] *= fr;
      }
    }
    float ps = 0.f;
    unsigned pk[2][8];
#pragma unroll
    for (int kb = 0; kb < 2; ++kb) {
      float e[16];
#pragma unroll
      for (int r = 0; r < 16; ++r) {
        e[r] = exp2f(S2[kb][r] - mq);
        ps += e[r];
      }
#pragma unroll
      for (int pp = 0; pp < 8; ++pp) pk[kb][pp] = cvtpk_bf16(e[2 * pp], e[2 * pp + 1]);
    }
    ps += __shfl_xor(ps, 32);
    lq += ps;
    // ---- PV: build A-frags in-register (elem e <-> key ks*16 + 8*half + e) ----
    __builtin_amdgcn_s_setprio(1);
#pragma unroll
    for (int ks = 0; ks < 4; ++ks) {
      const int kb = ks >> 1, kk = ks & 1;
      unsigned u_own = hh ? pk[kb][4 * kk + 2] : pk[kb][4 * kk + 0];
      unsigned v_own = hh ? pk[kb][4 * kk + 3] : pk[kb][4 * kk + 1];
      unsigned u_snd = hh ? pk[kb][4 * kk + 0] : pk[kb][4 * kk + 2];
      unsigned v_snd = hh ? pk[kb][4 * kk + 1] : pk[kb][4 * kk + 3];
      unsigned uo = (unsigned)__shfl_xor((int)u_snd, 32);
      unsigned vo = (unsigned)__shfl_xor((int)v_snd, 32);
      us8 pa = us8_from4(hh ? uo : u_own, hh ? vo : v_own, hh ? u_own : uo, hh ? v_own : vo);
#pragma unroll
      for (int db = 0; db < 4; ++db) {
        int d = db * 32 + q32;
        us8 vf = ld8(&VTs[cur][d * 64 + (((ks * 2 + hh) ^ (d & 7)) * 8)]);
        mfma32(O[db], pa, vf);
      }
    }
    __builtin_amdgcn_s_setprio(0);
  }
  // ---- epilogue: O[db] reg r -> row q = (r&3)+8*(r>>2)+4*hh, col d = db*32 + q32 ----
  float inv = 1.0f / lq;
#pragma unroll
  for (int r = 0; r < 16; ++r) {
    int qr = (r & 3) + 8 * (r >> 2) + 4 * hh;
    float ir = __shfl(inv, qr);
    size_t row = (size_t)b * 2048 + qt * 128 + w * 32 + qr;
#pragma unroll
    for (int db = 0; db < 4; ++db)
      Aout[row * 2048 + h * 128 + db * 32 + q32] = f2bf(O[db][r] * ir);
  }
}

extern "C" void kernel_launch(void* const* d_in, const int* in_sizes, int n_in, void* d_out,
                              int out_size, void* d_ws, size_t ws_size, hipStream_t stream) {
  (void)in_sizes; (void)n_in; (void)out_size; (void)ws_size;
  constexpr int Mr = 4096;
  using US = unsigned short;
  const float* x        = (const float*)d_in[0];
  const float* w_down_q = (const float*)d_in[1];
  const float* b_down_q = (const float*)d_in[2];
  const float* w_up_q   = (const float*)d_in[3];
  const float* b_up_q   = (const float*)d_in[4];
  const float* w_down_kv= (const float*)d_in[5];
  const float* b_down_kv= (const float*)d_in[6];
  const float* w_up_k   = (const float*)d_in[7];
  const float* b_up_k   = (const float*)d_in[8];
  const float* w_up_v   = (const float*)d_in[9];
  const float* b_up_v   = (const float*)d_in[10];
  const float* wq_r     = (const float*)d_in[11];
  const float* bq_r     = (const float*)d_in[12];
  const float* wk_r     = (const float*)d_in[13];
  const float* bk_r     = (const float*)d_in[14];
  const float* wo       = (const float*)d_in[15];
  const float* bo       = (const float*)d_in[16];

  char* p = (char*)d_ws;
  auto alloc = [&](size_t bytes) { char* r = p; p += (bytes + 255) & ~(size_t)255; return r; };
  // ---- round-9 proven layout: persistent buffers FIRST, aliasable region LAST ----
  float* cosT      = (float*)alloc((size_t)2048 * 1024 * 4);          //  8 MB
  float* sinT      = (float*)alloc((size_t)2048 * 1024 * 4);          //  8 MB
  US* wcat_kvup    = (US*)alloc((size_t)6144 * 512 * 2);              //  6 MB (live in G_kvup)
  US* wob          = (US*)alloc((size_t)2048 * 2048 * 2);             //  8 MB (live to G_out)
  US* ct           = (US*)alloc((size_t)Mr * 2048 * 2);               // 16 MB; aliased by aout
  US* t12          = (US*)alloc((size_t)Mr * 4096 * 2);               // 32 MB (live into attn)
  US* vtb          = (US*)alloc((size_t)Mr * 2048 * 2);               // 16 MB
  US* kb           = (US*)alloc((size_t)Mr * 2048 * 2);               // 16 MB
  float* bcat_down = (float*)alloc(2048 * 4);
  float* bcat_qup  = (float*)alloc(4096 * 4);
  float* bcat_kvup = (float*)alloc(6144 * 4);
  US* xb           = (US*)alloc((size_t)Mr * 2048 * 2);               // 16 MB }
  US* wcat_down    = (US*)alloc((size_t)2048 * 2048 * 2);             //  8 MB } kv3 (48MB)
  US* wcat_qup     = (US*)alloc((size_t)4096 * 1536 * 2);             // 12 MB } overlays
  alloc((size_t)12 * 1024 * 1024);                                    // 12 MB } tail pad
  US* kv3  = xb;    // 48MB = xb(16)+wcat_down(8)+wcat_qup(12)+pad(12); all dead before G_kvup
  US* aout = ct;    // ct dead after G_kvup

  // one fused prep dispatch: 9 cvts + freqs + bias concats
  k_prep<<<dim3(33804), dim3(256), 0, stream>>>(
      x, w_down_q, w_down_kv, w_up_q, wq_r, w_up_k, wk_r, w_up_v, wo, b_down_q, b_down_kv,
      b_up_q, bq_r, b_up_k, bk_r, b_up_v, xb, wcat_down, wcat_qup, wcat_kvup, wob, cosT, sinT,
      bcat_down, bcat_qup, bcat_kvup);

  // down-projection: ct = x . [wdq; wdkv]^T   (256 blocks)
  k_gemm256<false><<<dim3((2048 / 256) * (Mr / 128)), dim3(256), 0, stream>>>(
      xb, wcat_down, bcat_down, (void*)ct, 2048, 2048, 2048);
  // q up-projection: t12 = ctq . [wuq; wqr]^T  (512 blocks)
  k_gemm256<false><<<dim3((4096 / 256) * (Mr / 128)), dim3(256), 0, stream>>>(
      ct, wcat_qup, bcat_qup, (void*)t12, 4096, 1536, 2048);
  // kv up-projection: kv3 = ctkv . [wuk; wkr; wuv]^T  (768 blocks)
  k_gemm256<false><<<dim3((6144 / 256) * (Mr / 128)), dim3(256), 0, stream>>>(
      ct + 1536, wcat_kvup, bcat_kvup, (void*)kv3, 6144, 512, 2048);
  k_rope_combine<<<dim3((4096 * 1024 + 255) / 256), dim3(256), 0, stream>>>(kv3, 6144, cosT, sinT,
                                                                            kb);
  k_transpose_v<<<dim3(64, 128), dim3(256), 0, stream>>>(kv3 + 4096, 6144, vtb);
  // attention (q-RoPE fused) -> aout   [1-D grid, XCD-chunked for KV L2 residency]
  k_attn<<<dim3(512), dim3(256), 0, stream>>>(t12, kb, vtb, cosT, sinT, aout);
  // output projection (f32 out, 256 blocks)
  k_gemm256<true><<<dim3((2048 / 256) * (Mr / 128)), dim3(256), 0, stream>>>(
      aout, wob, bo, d_out, 2048, 2048, 2048);
}

// Round 16
// 358.377 us; speedup vs baseline: 1.0469x; 1.0032x over previous
//
#include <hip/hip_runtime.h>

typedef float f32x4 __attribute__((ext_vector_type(4)));
typedef float f32x16 __attribute__((ext_vector_type(16)));
typedef unsigned short us8 __attribute__((ext_vector_type(8)));

#define DEVINL __device__ __forceinline__

DEVINL unsigned short f2bf(float f) {
  unsigned u = __builtin_bit_cast(unsigned, f);
  u += 0x7fffu + ((u >> 16) & 1u);
  return (unsigned short)(u >> 16);
}
DEVINL float bf2f(unsigned short b) { return __builtin_bit_cast(float, ((unsigned)b) << 16); }
DEVINL us8 ld8(const unsigned short* p) { return *reinterpret_cast<const us8*>(p); }
DEVINL void mfma16(f32x4& acc, us8 a, us8 b) {
  asm("v_mfma_f32_16x16x32_bf16 %0, %1, %2, %0" : "+v"(acc) : "v"(a), "v"(b));
}
DEVINL void mfma32(f32x16& acc, us8 a, us8 b) {
  asm("v_mfma_f32_32x32x16_bf16 %0, %1, %2, %0" : "+v"(acc) : "v"(a), "v"(b));
}
DEVINL unsigned cvtpk_bf16(float lo, float hi) {
  unsigned r;
  asm("v_cvt_pk_bf16_f32 %0, %1, %2" : "=v"(r) : "v"(lo), "v"(hi));
  return r;
}
DEVINL us8 us8_from4(unsigned a, unsigned b, unsigned c, unsigned d) {
  union { unsigned u[4]; us8 v; } x;
  x.u[0] = a; x.u[1] = b; x.u[2] = c; x.u[3] = d;
  return x.v;
}
// async global->LDS, 16B per lane; LDS dest = base + lane*16 (wave-uniform base)
DEVINL void gld16(const void* g, void* l) {
  __builtin_amdgcn_global_load_lds((const __attribute__((address_space(1))) void*)g,
                                   (__attribute__((address_space(3))) void*)l, 16, 0, 0);
}

// ---------------- fused prep: all fp32->bf16 converts + bias concat + RoPE tables ------------
DEVINL void cvt4(const float* __restrict__ s, unsigned short* __restrict__ d, long i) {
  float4 v = reinterpret_cast<const float4*>(s)[i];
  unsigned lo = (unsigned)f2bf(v.x) | ((unsigned)f2bf(v.y) << 16);
  unsigned hi = (unsigned)f2bf(v.z) | ((unsigned)f2bf(v.w) << 16);
  reinterpret_cast<uint2*>(d)[i] = make_uint2(lo, hi);
}

__global__ void k_prep(const float* __restrict__ x, const float* __restrict__ wdq,
                       const float* __restrict__ wdkv, const float* __restrict__ wuq,
                       const float* __restrict__ wqr, const float* __restrict__ wuk,
                       const float* __restrict__ wkr, const float* __restrict__ wuv,
                       const float* __restrict__ wo, const float* __restrict__ bdq,
                       const float* __restrict__ bdkv, const float* __restrict__ buq,
                       const float* __restrict__ bqr, const float* __restrict__ buk,
                       const float* __restrict__ bkr, const float* __restrict__ buv,
                       unsigned short* __restrict__ xb, unsigned short* __restrict__ wcd,
                       unsigned short* __restrict__ wcq, unsigned short* __restrict__ wck,
                       unsigned short* __restrict__ wob, float* __restrict__ cosT,
                       float* __restrict__ sinT, float* __restrict__ bcd,
                       float* __restrict__ bcq, float* __restrict__ bck) {
  constexpr long C0 = 2097152, C1 = C0 + 786432, C2 = C1 + 262144, C3 = C2 + 786432,
                 C4 = C3 + 786432, C5 = C4 + 262144, C6 = C5 + 262144, C7 = C6 + 262144,
                 C8 = C7 + 1048576, C9 = C8 + 2097152, C10 = C9 + 3072;
  long u = (long)blockIdx.x * 256 + threadIdx.x;
  if (u < C0) cvt4(x, xb, u);
  else if (u < C1) cvt4(wdq, wcd, u - C0);
  else if (u < C2) cvt4(wdkv, wcd + 1536L * 2048, u - C1);
  else if (u < C3) cvt4(wuq, wcq, u - C2);
  else if (u < C4) cvt4(wqr, wcq + 2048L * 1536, u - C3);
  else if (u < C5) cvt4(wuk, wck, u - C4);
  else if (u < C6) cvt4(wkr, wck + 2048L * 512, u - C5);
  else if (u < C7) cvt4(wuv, wck + 4096L * 512, u - C6);
  else if (u < C8) cvt4(wo, wob, u - C7);
  else if (u < C9) {
    long idx = u - C8;
    int s = (int)(idx >> 10), i = (int)(idx & 1023);
    float e = (float)(2 * i);
    float pw = powf(10000.0f, e);  // overflow->inf -> tn=0, matches fp32 reference
    float tn = 1.0f / (pw / 2048.0f);
    float ang = (float)s * tn;
    cosT[idx] = cosf(ang);
    sinT[idx] = sinf(ang);
  } else if (u < C10) {
    long j4 = (u - C9) * 4;
#pragma unroll
    for (int k = 0; k < 4; ++k) {
      long j = j4 + k;
      if (j < 2048) {
        bcd[j] = j < 1536 ? bdq[j] : bdkv[j - 1536];
      } else if (j < 6144) {
        long jj = j - 2048;
        bcq[jj] = jj < 2048 ? buq[jj] : bqr[jj - 2048];
      } else {
        long jj = j - 6144;
        bck[jj] = jj < 2048 ? buk[jj] : (jj < 4096 ? bkr[jj - 2048] : buv[jj - 4096]);
      }
    }
  }
}

// ---- GEMM: C[M,N] = A[M,K](stride lda) * B[N,K]^T + bias. BM=128, BN in {128,256},
// THREADS = BN (2 or 4 waves), wave tile 64x128, 3-slot rotating LDS pipeline with
// counted vmcnt (stage lead 2), chunk-XOR swizzle. Bit-identical math for both BN. ----
template <int BN, bool OUTF32>
__global__ __launch_bounds__(BN) void k_gemm256(const unsigned short* __restrict__ A,
                                                const unsigned short* __restrict__ B,
                                                const float* __restrict__ bias,
                                                void* __restrict__ Cout, int N, int K, int lda) {
  constexpr int THREADS = BN;           // 128 -> 2 waves, 256 -> 4 waves
  constexpr int WN = BN / 128;          // wave-cols
  constexpr int NA = 512 / THREADS;     // A-chunks per thread
  constexpr int NB = BN * 4 / THREADS;  // B-chunks per thread (= 4)
  constexpr int SLOT = 128 * 32 + BN * 32;  // shorts
  __shared__ unsigned short lds[3 * SLOT];
  const int nwg = gridDim.x;
  const int orig = blockIdx.x;
  const int wgid = (orig & 7) * (nwg >> 3) + (orig >> 3);  // XCD-chunked (nwg % 8 == 0)
  const int nbn = N / BN;
  const int bn = wgid % nbn, bm = wgid / nbn;
  const int tid = threadIdx.x, lane = tid & 63, w = tid >> 6;
  const int g = lane >> 4, l16 = lane & 15;
  const int wm = w / WN, wn = w % WN;
  f32x4 acc[4][8] = {};
  const unsigned short* Abase = A + (size_t)bm * 128 * lda;
  const unsigned short* Bbase = B + (size_t)bn * BN * K;
  // staging: LDS chunk c <- global col-chunk (c&3)^((row>>1)&3)  [involution]
  size_t aoff[NA], boff[NB];
#pragma unroll
  for (int j = 0; j < NA; ++j) {
    int c = j * THREADS + tid;
    int row = c >> 2, gc = (c & 3) ^ ((row >> 1) & 3);
    aoff[j] = (size_t)row * lda + gc * 8;
  }
#pragma unroll
  for (int j = 0; j < NB; ++j) {
    int cb = j * THREADS + tid;
    int row = cb >> 2, gc = (cb & 3) ^ ((row >> 1) & 3);
    boff[j] = (size_t)row * K + gc * 8;
  }
  auto STAGE = [&](int slot, int kt) {
    unsigned short* s = &lds[slot * SLOT];
#pragma unroll
    for (int j = 0; j < NA; ++j) gld16(Abase + aoff[j] + kt, s + (j * THREADS + tid) * 8);
#pragma unroll
    for (int j = 0; j < NB; ++j)
      gld16(Bbase + boff[j] + kt, s + 128 * 32 + (j * THREADS + tid) * 8);
  };
  const int nt = K >> 5;
  STAGE(0, 0);
  STAGE(1, 32);
  if (BN == 256) asm volatile("s_waitcnt vmcnt(6)" ::: "memory");
  else           asm volatile("s_waitcnt vmcnt(8)" ::: "memory");
  asm volatile("s_barrier" ::: "memory");
  for (int t = 0; t < nt; ++t) {
    const int slot = t % 3;
    if (t + 2 < nt) STAGE((t + 2) % 3, (t + 2) * 32);
    const unsigned short* sa = &lds[slot * SLOT];
    const unsigned short* sb = sa + 128 * 32;
    us8 af[4], bf[8];
#pragma unroll
    for (int m = 0; m < 4; ++m) {
      int row = wm * 64 + m * 16 + l16;
      af[m] = ld8(&sa[row * 32 + ((g ^ ((row >> 1) & 3)) * 8)]);
    }
#pragma unroll
    for (int n = 0; n < 8; ++n) {
      int row = wn * 128 + n * 16 + l16;
      bf[n] = ld8(&sb[row * 32 + ((g ^ ((row >> 1) & 3)) * 8)]);
    }
    __builtin_amdgcn_s_setprio(1);
#pragma unroll
    for (int m = 0; m < 4; ++m)
#pragma unroll
      for (int n = 0; n < 8; ++n) mfma16(acc[m][n], af[m], bf[n]);
    __builtin_amdgcn_s_setprio(0);
    if (t < nt - 2) {
      if (BN == 256) asm volatile("s_waitcnt vmcnt(6)" ::: "memory");
      else           asm volatile("s_waitcnt vmcnt(8)" ::: "memory");
    } else {
      asm volatile("s_waitcnt vmcnt(0)" ::: "memory");
    }
    asm volatile("s_barrier" ::: "memory");
  }
#pragma unroll
  for (int n = 0; n < 8; ++n) {
    int col = bn * BN + wn * 128 + n * 16 + l16;
    float bv = bias[col];
#pragma unroll
    for (int m = 0; m < 4; ++m) {
      int row0 = bm * 128 + wm * 64 + m * 16 + g * 4;
#pragma unroll
      for (int r = 0; r < 4; ++r) {
        float vv = acc[m][n][r] + bv;
        if (OUTF32)
          reinterpret_cast<float*>(Cout)[(size_t)(row0 + r) * N + col] = vv;
        else
          reinterpret_cast<unsigned short*>(Cout)[(size_t)(row0 + r) * N + col] = f2bf(vv);
      }
    }
  }
}

// ---- k = ct + rope(rl): src row holds [ct (2048) | rl (2048) | ...], width ldin ----
__global__ void k_rope_combine(const unsigned short* __restrict__ src, int ldin,
                               const float* __restrict__ cosT, const float* __restrict__ sinT,
                               unsigned short* __restrict__ outp) {
  int pidx = blockIdx.x * 256 + threadIdx.x;  // pair index
  if (pidx >= 4096 * 1024) return;
  int row = pidx >> 10, i = pidx & 1023;
  int s = row & 2047;
  float c = cosT[s * 1024 + i], sn = sinT[s * 1024 + i];
  const unsigned short* rp = src + (size_t)row * ldin;
  float xe = bf2f(rp[2048 + 2 * i]), xo = bf2f(rp[2048 + 2 * i + 1]);
  float re = xe * c - xo * sn;
  float im = xe * sn + xo * c;
  float q0 = bf2f(rp[2 * i]) + re;
  float q1 = bf2f(rp[2 * i + 1]) + im;
  unsigned pack = (unsigned)f2bf(q0) | ((unsigned)f2bf(q1) << 16);
  *reinterpret_cast<unsigned*>(&outp[(size_t)row * 2048 + 2 * i]) = pack;
}

// ---------------- V transpose: v[4096][cols of width ld] -> vt[b][h][d][s] ----------------
__global__ __launch_bounds__(256) void k_transpose_v(const unsigned short* __restrict__ v, int ld,
                                                     unsigned short* __restrict__ vt) {
  __shared__ unsigned short t[32][33];
  int tx = threadIdx.x & 31, ty = threadIdx.x >> 5;
  int r0 = blockIdx.y * 32, c0 = blockIdx.x * 32;
#pragma unroll
  for (int jj = 0; jj < 4; ++jj)
    t[ty * 4 + jj][tx] = v[(size_t)(r0 + ty * 4 + jj) * ld + c0 + tx];
  __syncthreads();
  int b = r0 >> 11;
#pragma unroll
  for (int jj = 0; jj < 4; ++jj) {
    int colc = c0 + ty * 4 + jj;
    size_t orow = (size_t)(b * 16 + (colc >> 7)) * 128 + (colc & 127);
    vt[orow * 2048 + (r0 & 2047) + tx] = t[tx][ty * 4 + jj];
  }
}

// ------ flash attention, 32x32 MFMA: 4 waves x 32 q-rows, KV tile 64, in-register P ------
// Q read from t12 ([q_ct | rope_raw], ldin 4096) with fused RoPE and *SC2 pre-scale.
// C/D layout (m74/m101): col=lane&31, row=(reg&3)+8*(reg>>2)+4*(lane>>5).
// Grid: 1-D 512 blocks, XCD-chunked so each XCD owns 4 (h,b) groups (KV L2-resident).
__global__ __launch_bounds__(256, 2) void k_attn(const unsigned short* __restrict__ Qsrc,
                                                 const unsigned short* __restrict__ Kg,
                                                 const unsigned short* __restrict__ VT,
                                                 const float* __restrict__ cosT,
                                                 const float* __restrict__ sinT,
                                                 unsigned short* __restrict__ Aout) {
  __shared__ unsigned short Ks[2][64 * 128];
  __shared__ unsigned short VTs[2][128 * 64];
  const int tid = threadIdx.x, lane = tid & 63, w = tid >> 6;
  const int hh = lane >> 5, q32 = lane & 31;
  // numerics-neutral block remap: blocks independent; only locality changes
  const int orig = blockIdx.x;
  const int wgid = (orig & 7) * 64 + (orig >> 3);
  const int qt = wgid & 15;
  const int hb = wgid >> 4;      // 0..31: 4 consecutive per XCD
  const int h = hb & 15, b = hb >> 4;
  const float SC2 = 0.08838834764831845f * 1.4426950408889634f;  // (1/sqrt(128))*log2(e)
  const int srow = qt * 128 + w * 32 + q32;  // seq position
  // ---- Q load with fused RoPE: qf[ds] = Q[q=q32][d = ds*16 + hh*8 + 0..7] ----
  us8 qf[8];
  {
    const unsigned short* Qr = Qsrc + ((size_t)b * 2048 + srow) * 4096;
#pragma unroll
    for (int ds = 0; ds < 8; ++ds) {
      int dcol = h * 128 + ds * 16 + hh * 8;
      us8 c8 = ld8(&Qr[dcol]);
      us8 r8 = ld8(&Qr[2048 + dcol]);
      unsigned wv[4];
#pragma unroll
      for (int p2 = 0; p2 < 4; ++p2) {
        int i = (dcol >> 1) + p2;
        float cc = cosT[srow * 1024 + i], ss = sinT[srow * 1024 + i];
        float xe = bf2f(r8[2 * p2]), xo = bf2f(r8[2 * p2 + 1]);
        float o0 = (bf2f(c8[2 * p2]) + xe * cc - xo * ss) * SC2;
        float o1 = (bf2f(c8[2 * p2 + 1]) + xe * ss + xo * cc) * SC2;
        wv[p2] = cvtpk_bf16(o0, o1);
      }
      qf[ds] = us8_from4(wv[0], wv[1], wv[2], wv[3]);
    }
  }
  f32x16 O[4] = {};
  float mq = -1e30f, lq = 0.f;
  const unsigned short* Kbase = Kg + (size_t)b * 2048 * 2048 + h * 128;
  const unsigned short* VTb = VT + (size_t)(b * 16 + h) * 128 * 2048;
  auto STAGE = [&](int bufi, int ktrow) {
#pragma unroll
    for (int j = 0; j < 4; ++j) {
      int ch = (j * 4 + w) * 64 + lane;
      int key = ch >> 4, cp = ch & 15;  // K tile: 64 rows x 16 chunks, XOR key&15
      gld16(&Kbase[(size_t)(ktrow + key) * 2048 + (size_t)((cp ^ (key & 15)) * 8)],
            &Ks[bufi][(j * 4 + w) * 512]);
      int d = ch >> 3, c2 = ch & 7;     // VT tile: 128 rows x 8 chunks, XOR d&7
      gld16(&VTb[(size_t)d * 2048 + ktrow + (size_t)((c2 ^ (d & 7)) * 8)],
            &VTs[bufi][(j * 4 + w) * 512]);
    }
  };
  STAGE(0, 0);
  for (int t = 0; t < 32; ++t) {
    const int cur = t & 1;
    __syncthreads();
    if (t < 31) STAGE(cur ^ 1, (t + 1) * 64);
    // ---- QK^T swapped: S2[kb] reg r = S[key = kb*32 + (r&3)+8*(r>>2)+4*hh][q = q32] ----
    f32x16 S2[2] = {};
    __builtin_amdgcn_s_setprio(1);
#pragma unroll
    for (int kb = 0; kb < 2; ++kb) {
      const int key = kb * 32 + q32;
      const int swz = key & 15;
#pragma unroll
      for (int ds = 0; ds < 8; ++ds) {
        us8 kf = ld8(&Ks[cur][key * 128 + (((ds * 2 + hh) ^ swz) * 8)]);
        mfma32(S2[kb], kf, qf[ds]);
      }
    }
    __builtin_amdgcn_s_setprio(0);
    // ---- softmax (per q = q32; both halves hold same stats after xor-32 reduce) ----
    float mx[16];
#pragma unroll
    for (int r = 0; r < 16; ++r) mx[r] = fmaxf(S2[0][r], S2[1][r]);
#pragma unroll
    for (int st = 8; st > 0; st >>= 1)
#pragma unroll
      for (int r = 0; r < st; ++r) mx[r] = fmaxf(mx[r], mx[r + st]);
    float smax = fmaxf(mx[0], __shfl_xor(mx[0], 32));
    if (!__all(smax <= mq + 8.0f)) {  // defer-max
      float mn = fmaxf(mq, smax);
      float fac = exp2f(mq - mn);
      lq *= fac;
      mq = mn;
#pragma unroll
      for (int r = 0; r < 16; ++r) {
        int qr = (r & 3) + 8 * (r >> 2) + 4 * hh;
        float fr = __shfl(fac, qr);
#pragma unroll
        for (int db = 0; db < 4; ++db) O[db][r] *= fr;
      }
    }
    float ps = 0.f;
    unsigned pk[2][8];
#pragma unroll
    for (int kb = 0; kb < 2; ++kb) {
      float e[16];
#pragma unroll
      for (int r = 0; r < 16; ++r) {
        e[r] = exp2f(S2[kb][r] - mq);
        ps += e[r];
      }
#pragma unroll
      for (int pp = 0; pp < 8; ++pp) pk[kb][pp] = cvtpk_bf16(e[2 * pp], e[2 * pp + 1]);
    }
    ps += __shfl_xor(ps, 32);
    lq += ps;
    // ---- PV: build A-frags in-register (elem e <-> key ks*16 + 8*half + e) ----
    __builtin_amdgcn_s_setprio(1);
#pragma unroll
    for (int ks = 0; ks < 4; ++ks) {
      const int kb = ks >> 1, kk = ks & 1;
      unsigned u_own = hh ? pk[kb][4 * kk + 2] : pk[kb][4 * kk + 0];
      unsigned v_own = hh ? pk[kb][4 * kk + 3] : pk[kb][4 * kk + 1];
      unsigned u_snd = hh ? pk[kb][4 * kk + 0] : pk[kb][4 * kk + 2];
      unsigned v_snd = hh ? pk[kb][4 * kk + 1] : pk[kb][4 * kk + 3];
      unsigned uo = (unsigned)__shfl_xor((int)u_snd, 32);
      unsigned vo = (unsigned)__shfl_xor((int)v_snd, 32);
      us8 pa = us8_from4(hh ? uo : u_own, hh ? vo : v_own, hh ? u_own : uo, hh ? v_own : vo);
#pragma unroll
      for (int db = 0; db < 4; ++db) {
        int d = db * 32 + q32;
        us8 vf = ld8(&VTs[cur][d * 64 + (((ks * 2 + hh) ^ (d & 7)) * 8)]);
        mfma32(O[db], pa, vf);
      }
    }
    __builtin_amdgcn_s_setprio(0);
  }
  // ---- epilogue: O[db] reg r -> row q = (r&3)+8*(r>>2)+4*hh, col d = db*32 + q32 ----
  float inv = 1.0f / lq;
#pragma unroll
  for (int r = 0; r < 16; ++r) {
    int qr = (r & 3) + 8 * (r >> 2) + 4 * hh;
    float ir = __shfl(inv, qr);
    size_t row = (size_t)b * 2048 + qt * 128 + w * 32 + qr;
#pragma unroll
    for (int db = 0; db < 4; ++db)
      Aout[row * 2048 + h * 128 + db * 32 + q32] = f2bf(O[db][r] * ir);
  }
}

extern "C" void kernel_launch(void* const* d_in, const int* in_sizes, int n_in, void* d_out,
                              int out_size, void* d_ws, size_t ws_size, hipStream_t stream) {
  (void)in_sizes; (void)n_in; (void)out_size; (void)ws_size;
  constexpr int Mr = 4096;
  using US = unsigned short;
  const float* x        = (const float*)d_in[0];
  const float* w_down_q = (const float*)d_in[1];
  const float* b_down_q = (const float*)d_in[2];
  const float* w_up_q   = (const float*)d_in[3];
  const float* b_up_q   = (const float*)d_in[4];
  const float* w_down_kv= (const float*)d_in[5];
  const float* b_down_kv= (const float*)d_in[6];
  const float* w_up_k   = (const float*)d_in[7];
  const float* b_up_k   = (const float*)d_in[8];
  const float* w_up_v   = (const float*)d_in[9];
  const float* b_up_v   = (const float*)d_in[10];
  const float* wq_r     = (const float*)d_in[11];
  const float* bq_r     = (const float*)d_in[12];
  const float* wk_r     = (const float*)d_in[13];
  const float* bk_r     = (const float*)d_in[14];
  const float* wo       = (const float*)d_in[15];
  const float* bo       = (const float*)d_in[16];

  char* p = (char*)d_ws;
  auto alloc = [&](size_t bytes) { char* r = p; p += (bytes + 255) & ~(size_t)255; return r; };
  // ---- round-9 proven layout: persistent buffers FIRST, aliasable region LAST ----
  float* cosT      = (float*)alloc((size_t)2048 * 1024 * 4);          //  8 MB
  float* sinT      = (float*)alloc((size_t)2048 * 1024 * 4);          //  8 MB
  US* wcat_kvup    = (US*)alloc((size_t)6144 * 512 * 2);              //  6 MB (live in G_kvup)
  US* wob          = (US*)alloc((size_t)2048 * 2048 * 2);             //  8 MB (live to G_out)
  US* ct           = (US*)alloc((size_t)Mr * 2048 * 2);               // 16 MB; aliased by aout
  US* t12          = (US*)alloc((size_t)Mr * 4096 * 2);               // 32 MB (live into attn)
  US* vtb          = (US*)alloc((size_t)Mr * 2048 * 2);               // 16 MB
  US* kb           = (US*)alloc((size_t)Mr * 2048 * 2);               // 16 MB
  float* bcat_down = (float*)alloc(2048 * 4);
  float* bcat_qup  = (float*)alloc(4096 * 4);
  float* bcat_kvup = (float*)alloc(6144 * 4);
  US* xb           = (US*)alloc((size_t)Mr * 2048 * 2);               // 16 MB }
  US* wcat_down    = (US*)alloc((size_t)2048 * 2048 * 2);             //  8 MB } kv3 (48MB)
  US* wcat_qup     = (US*)alloc((size_t)4096 * 1536 * 2);             // 12 MB } overlays
  alloc((size_t)12 * 1024 * 1024);                                    // 12 MB } tail pad
  US* kv3  = xb;    // 48MB = xb(16)+wcat_down(8)+wcat_qup(12)+pad(12); all dead before G_kvup
  US* aout = ct;    // ct dead after G_kvup

  // one fused prep dispatch: 9 cvts + freqs + bias concats
  k_prep<<<dim3(33804), dim3(256), 0, stream>>>(
      x, w_down_q, w_down_kv, w_up_q, wq_r, w_up_k, wk_r, w_up_v, wo, b_down_q, b_down_kv,
      b_up_q, bq_r, b_up_k, bk_r, b_up_v, xb, wcat_down, wcat_qup, wcat_kvup, wob, cosT, sinT,
      bcat_down, bcat_qup, bcat_kvup);

  // down-projection: ct = x . [wdq; wdkv]^T   (BN=128 -> 512 blocks, 2/CU)
  k_gemm256<128, false><<<dim3((2048 / 128) * (Mr / 128)), dim3(128), 0, stream>>>(
      xb, wcat_down, bcat_down, (void*)ct, 2048, 2048, 2048);
  // q up-projection: t12 = ctq . [wuq; wqr]^T  (BN=256 -> 512 blocks)
  k_gemm256<256, false><<<dim3((4096 / 256) * (Mr / 128)), dim3(256), 0, stream>>>(
      ct, wcat_qup, bcat_qup, (void*)t12, 4096, 1536, 2048);
  // kv up-projection: kv3 = ctkv . [wuk; wkr; wuv]^T  (BN=256 -> 768 blocks)
  k_gemm256<256, false><<<dim3((6144 / 256) * (Mr / 128)), dim3(256), 0, stream>>>(
      ct + 1536, wcat_kvup, bcat_kvup, (void*)kv3, 6144, 512, 2048);
  k_rope_combine<<<dim3((4096 * 1024 + 255) / 256), dim3(256), 0, stream>>>(kv3, 6144, cosT, sinT,
                                                                            kb);
  k_transpose_v<<<dim3(64, 128), dim3(256), 0, stream>>>(kv3 + 4096, 6144, vtb);
  // attention (q-RoPE fused) -> aout   [1-D grid, XCD-chunked for KV L2 residency]
  k_attn<<<dim3(512), dim3(256), 0, stream>>>(t12, kb, vtb, cosT, sinT, aout);
  // output projection (f32 out, BN=128 -> 512 blocks, 2/CU)
  k_gemm256<128, true><<<dim3((2048 / 128) * (Mr / 128)), dim3(128), 0, stream>>>(
      aout, wob, bo, d_out, 2048, 2048, 2048);
}